// Round 8
// baseline (547.629 us; speedup 1.0000x reference)
//
#include <hip/hip_runtime.h>
#include <cstdint>

#define L_SEQ 2304
#define CDIM  512
#define NHEADS 8
#define HD    64
#define LL    ((size_t)L_SEQ * L_SEQ)

typedef short  s8v  __attribute__((ext_vector_type(8)));
typedef float  f4v  __attribute__((ext_vector_type(4)));

__device__ __forceinline__ ushort f2bf(float f) {
    union { float f; uint32_t u; } v; v.f = f;
    uint32_t u = v.u;
    uint32_t r = (u + 0x7FFFu + ((u >> 16) & 1u)) >> 16;
    return (ushort)r;
}
__device__ __forceinline__ float bf2f(ushort h) {
    union { uint32_t u; float f; } v; v.u = ((uint32_t)h) << 16;
    return v.f;
}

// ==================================================================
// W -> (hi, lo) bf16 planes. grid (128, 4), block 256.
__global__ __launch_bounds__(256) void conv_w(
    const float* __restrict__ Wq, const float* __restrict__ Wk,
    const float* __restrict__ Wv, const float* __restrict__ Wo,
    ushort* __restrict__ wbh, ushort* __restrict__ wbl)
{
    const int m = blockIdx.y;
    const float* src = (m == 0) ? Wq : (m == 1) ? Wk : (m == 2) ? Wv : Wo;
    const size_t idx = ((size_t)blockIdx.x * 256 + threadIdx.x) * 8;
    float v[8];
    *(float4*)&v[0] = *(const float4*)&src[idx];
    *(float4*)&v[4] = *(const float4*)&src[idx + 4];
    ushort hh[8], ll[8];
    #pragma unroll
    for (int i = 0; i < 8; i++) {
        hh[i] = f2bf(v[i]);
        ll[i] = f2bf(v[i] - bf2f(hh[i]));
    }
    const size_t off = (size_t)m * CDIM * CDIM + idx;
    *(ushort4*)&wbh[off]     = *(ushort4*)&hh[0];
    *(ushort4*)&wbh[off + 4] = *(ushort4*)&hh[4];
    *(ushort4*)&wbl[off]     = *(ushort4*)&ll[0];
    *(ushort4*)&wbl[off + 4] = *(ushort4*)&ll[4];
}

// ==================================================================
// Xt_hi/lo[b][l][c] = split_bf16(x[b][c][l] + pos[c][l]). grid (36,8,2), 256.
__global__ __launch_bounds__(256) void prep_xt(
    const float* __restrict__ x, const float* __restrict__ pos,
    ushort* __restrict__ xth, ushort* __restrict__ xtl)
{
    __shared__ float Ts[64][68];
    const int l0 = blockIdx.x * 64;
    const int c0 = blockIdx.y * 64;
    const int b  = blockIdx.z;
    const int t  = threadIdx.x;

    const float* xb = x + (size_t)b * CDIM * L_SEQ;
    #pragma unroll
    for (int r = 0; r < 4; r++) {
        const int cl = (t >> 4) + r * 16;
        const int ll = (t & 15) * 4;
        const size_t off = (size_t)(c0 + cl) * L_SEQ + l0 + ll;
        float4 xv = *(const float4*)&xb[off];
        const float4 pv = *(const float4*)&pos[off];
        xv.x += pv.x; xv.y += pv.y; xv.z += pv.z; xv.w += pv.w;
        *(float4*)&Ts[cl][ll] = xv;
    }
    __syncthreads();
    #pragma unroll
    for (int r = 0; r < 4; r++) {
        const int ll = (t >> 4) + r * 16;
        const int cl = (t & 15) * 4;
        ushort4 sh, sl;
        float vv[4];
        #pragma unroll
        for (int i = 0; i < 4; i++) vv[i] = Ts[cl + i][ll];
        sh.x = f2bf(vv[0]); sh.y = f2bf(vv[1]); sh.z = f2bf(vv[2]); sh.w = f2bf(vv[3]);
        sl.x = f2bf(vv[0] - bf2f(sh.x));
        sl.y = f2bf(vv[1] - bf2f(sh.y));
        sl.z = f2bf(vv[2] - bf2f(sh.z));
        sl.w = f2bf(vv[3] - bf2f(sh.w));
        const size_t off = ((size_t)b * L_SEQ + l0 + ll) * CDIM + c0 + cl;
        *(ushort4*)&xth[off] = sh;
        *(ushort4*)&xtl[off] = sl;
    }
}

// ==================================================================
// QKV projection, split-bf16 MFMA (fp32-accurate). grid (36, 24, 2), block 256.
__global__ __launch_bounds__(256) void qkv_mfma(
    const ushort* __restrict__ wbh, const ushort* __restrict__ wbl,
    const ushort* __restrict__ xth, const ushort* __restrict__ xtl,
    const float* __restrict__ bq, const float* __restrict__ bk,
    const float* __restrict__ bv,
    ushort* __restrict__ q_t, ushort* __restrict__ k_t, ushort* __restrict__ v_t)
{
    const int l0    = blockIdx.x * 64;
    const int wtype = blockIdx.y >> 3;
    const int h     = blockIdx.y & 7;
    const int b     = blockIdx.z;
    const int t     = threadIdx.x;
    const int w     = t >> 6;
    const int lane  = t & 63;
    const int n16   = lane & 15;
    const int q4    = lane >> 4;

    const size_t wro = (size_t)wtype * CDIM * CDIM
                     + (size_t)(h * 64 + w * 16 + n16) * CDIM;
    const ushort* wrh = wbh + wro;
    const ushort* wrl = wbl + wro;
    size_t xro[4];
    #pragma unroll
    for (int t4 = 0; t4 < 4; t4++)
        xro[t4] = ((size_t)b * L_SEQ + l0 + t4 * 16 + n16) * CDIM;

    f4v acc[4] = {{0.f,0.f,0.f,0.f},{0.f,0.f,0.f,0.f},{0.f,0.f,0.f,0.f},{0.f,0.f,0.f,0.f}};
    #pragma unroll
    for (int ks = 0; ks < 16; ks++) {
        const int co = ks * 32 + q4 * 8;
        const s8v afh = *(const s8v*)&wrh[co];
        const s8v afl = *(const s8v*)&wrl[co];
        #pragma unroll
        for (int t4 = 0; t4 < 4; t4++) {
            const s8v bfh = *(const s8v*)&xth[xro[t4] + co];
            const s8v bfl = *(const s8v*)&xtl[xro[t4] + co];
            acc[t4] = __builtin_amdgcn_mfma_f32_16x16x32_bf16(afh, bfh, acc[t4], 0, 0, 0);
            acc[t4] = __builtin_amdgcn_mfma_f32_16x16x32_bf16(afl, bfh, acc[t4], 0, 0, 0);
            acc[t4] = __builtin_amdgcn_mfma_f32_16x16x32_bf16(afh, bfl, acc[t4], 0, 0, 0);
        }
    }

    const float* bias = (wtype == 0) ? bq : (wtype == 1) ? bk : bv;
    float bi[4];
    #pragma unroll
    for (int r = 0; r < 4; r++) bi[r] = bias[h * 64 + w * 16 + q4 * 4 + r];

    if (wtype < 2) {
        const float sc = (wtype == 0) ? 0.125f : 1.0f;
        ushort* op = (wtype == 0 ? q_t : k_t) + (size_t)(b * NHEADS + h) * L_SEQ * HD;
        #pragma unroll
        for (int t4 = 0; t4 < 4; t4++) {
            const int l = l0 + t4 * 16 + n16;
            ushort4 st;
            st.x = f2bf((acc[t4][0] + bi[0]) * sc);
            st.y = f2bf((acc[t4][1] + bi[1]) * sc);
            st.z = f2bf((acc[t4][2] + bi[2]) * sc);
            st.w = f2bf((acc[t4][3] + bi[3]) * sc);
            *(ushort4*)&op[(size_t)l * HD + w * 16 + q4 * 4] = st;
        }
    } else {
        ushort* op = v_t + (size_t)(b * NHEADS + h) * HD * L_SEQ;
        #pragma unroll
        for (int t4 = 0; t4 < 4; t4++) {
            const int l = l0 + t4 * 16 + n16;
            #pragma unroll
            for (int r = 0; r < 4; r++)
                op[(size_t)(w * 16 + q4 * 4 + r) * L_SEQ + l] = f2bf(acc[t4][r] + bi[r]);
        }
    }
}

// ==================================================================
// R3-VERBATIM flash attention. Block = 256 threads (4 waves), 64 q-rows of
// one (b,h). K-tile = 64 keys staged to LDS in MFMA-fragment order.
// grid 576 (1D), block 256. fp32 attn out (b,h,l,d).
__global__ __launch_bounds__(256) void flash_attn_mfma(
    const ushort* __restrict__ q, const ushort* __restrict__ k,
    const ushort* __restrict__ vt, const int* __restrict__ mask,
    const float* __restrict__ rel_table, float* __restrict__ attn_out)
{
    __shared__ __align__(16) ushort Kf[512 * 8];   // B-frags for S
    __shared__ __align__(16) ushort Vf[512 * 8];   // B-frags for PV
    __shared__ __align__(16) ushort Pb[4 * 16 * 72]; // per-wave P, row-major [16][72]
    __shared__ float rt[65];

    const int t    = threadIdx.x;
    const int id   = blockIdx.x;
    const int h    = id & 7;            // XCD-pinned head
    const int slot = id >> 3;
    const int b    = slot & 1;          // adjacent slots share mask rows (L2 reuse)
    const int qb   = slot >> 1;
    const int bh   = b * NHEADS + h;
    const int l0   = qb * 64;
    const int w    = t >> 6;
    const int lane = t & 63;
    const int n16  = lane & 15;
    const int q4   = lane >> 4;

    if (t < 65) rt[t] = rel_table[h * 65 + t];

    const ushort* qp = q  + (size_t)bh * L_SEQ * HD;
    const ushort* kp = k  + (size_t)bh * L_SEQ * HD;
    const ushort* vp = vt + (size_t)bh * HD * L_SEQ;
    const int*    mp = mask + (size_t)h * LL;

    // Q A-fragments: A[m=lane&15][k=quad*8+j], rows l0+w*16+n16
    const int qrow = l0 + w * 16 + n16;
    const s8v qA0 = *(const s8v*)&qp[(size_t)qrow * HD + q4 * 8];
    const s8v qA1 = *(const s8v*)&qp[(size_t)qrow * HD + 32 + q4 * 8];

    f4v O[4] = {{0.f,0.f,0.f,0.f},{0.f,0.f,0.f,0.f},{0.f,0.f,0.f,0.f},{0.f,0.f,0.f,0.f}};
    float mrun[4] = {-3e38f, -3e38f, -3e38f, -3e38f};
    float lrun[4] = {0.f, 0.f, 0.f, 0.f};

    // precompute this thread's two staging chunk decodes (c = t, t+256)
    int sT[2], sS[2], sQ[2], sN[2];
    #pragma unroll
    for (int cc = 0; cc < 2; cc++) {
        const int c = t + cc * 256;
        const int g = c >> 6;
        sT[cc] = g >> 1; sS[cc] = g & 1;
        sQ[cc] = (c >> 4) & 3; sN[cc] = c & 15;
    }

    const int rowbase = l0 + w * 16 + q4 * 4;   // +r gives the C-layout row

    for (int mt = 0; mt < L_SEQ / 64; mt++) {
        const int mb = mt * 64;
        __syncthreads();   // WAR: previous tile's reads done before restage
        #pragma unroll
        for (int cc = 0; cc < 2; cc++) {
            const int c = t + cc * 256;
            const int key = sT[cc] * 16 + sN[cc];
            const int d0  = sS[cc] * 32 + sQ[cc] * 8;
            *(s8v*)&Kf[c * 8] = *(const s8v*)&kp[(size_t)(mb + key) * HD + d0];
            const int dd = sT[cc] * 16 + sN[cc];
            *(s8v*)&Vf[c * 8] = *(const s8v*)&vp[(size_t)dd * L_SEQ + mb + d0];
        }
        __syncthreads();

        // mask loads (int32 per harness bool convention)
        int mreg[4][4];
        #pragma unroll
        for (int t4 = 0; t4 < 4; t4++)
            #pragma unroll
            for (int r = 0; r < 4; r++)
                mreg[t4][r] = mp[(size_t)(rowbase + r) * L_SEQ + mb + t4 * 16 + n16];

        // S = Q K^T  (C layout: col=lane&15 -> key t4*16+n16, row=q4*4+r)
        f4v S[4];
        #pragma unroll
        for (int t4 = 0; t4 < 4; t4++) {
            const s8v b0 = *(const s8v*)&Kf[((t4 * 2 + 0) * 64 + lane) * 8];
            const s8v b1 = *(const s8v*)&Kf[((t4 * 2 + 1) * 64 + lane) * 8];
            f4v acc = {0.f, 0.f, 0.f, 0.f};
            acc = __builtin_amdgcn_mfma_f32_16x16x32_bf16(qA0, b0, acc, 0, 0, 0);
            acc = __builtin_amdgcn_mfma_f32_16x16x32_bf16(qA1, b1, acc, 0, 0, 0);
            S[t4] = acc;
        }

        // relative positional bias then mask -> exactly -1e9 (ref order)
        #pragma unroll
        for (int t4 = 0; t4 < 4; t4++) {
            const int A = (l0 + w * 16) - (mb + t4 * 16);
            if (A >= 47) {
                const float bu = rt[64];
                #pragma unroll
                for (int r = 0; r < 4; r++) S[t4][r] += bu;
            } else if (A <= -47) {
                const float bu = rt[0];
                #pragma unroll
                for (int r = 0; r < 4; r++) S[t4][r] += bu;
            } else {
                #pragma unroll
                for (int r = 0; r < 4; r++) {
                    int dix = A + q4 * 4 + r - n16;
                    dix = min(max(dix, -32), 32) + 32;
                    S[t4][r] += rt[dix];
                }
            }
            #pragma unroll
            for (int r = 0; r < 4; r++)
                if (mreg[t4][r] == 0) S[t4][r] = -1e9f;
        }

        // online softmax per row (row stats replicated over 16 lanes of quad)
        float mx[4];
        #pragma unroll
        for (int r = 0; r < 4; r++) {
            float m0 = fmaxf(fmaxf(S[0][r], S[1][r]), fmaxf(S[2][r], S[3][r]));
            m0 = fmaxf(m0, __shfl_xor(m0, 1));
            m0 = fmaxf(m0, __shfl_xor(m0, 2));
            m0 = fmaxf(m0, __shfl_xor(m0, 4));
            m0 = fmaxf(m0, __shfl_xor(m0, 8));
            mx[r] = m0;
        }
        float al[4];
        #pragma unroll
        for (int r = 0; r < 4; r++) {
            const float mn = fmaxf(mrun[r], mx[r]);
            al[r] = __expf(mrun[r] - mn);
            mrun[r] = mn;
            float sum = 0.f;
            #pragma unroll
            for (int t4 = 0; t4 < 4; t4++) {
                const float p = __expf(S[t4][r] - mn);
                S[t4][r] = p;
                sum += p;
                Pb[w * 1152 + (q4 * 4 + r) * 72 + t4 * 16 + n16] = f2bf(p);
            }
            sum += __shfl_xor(sum, 1);
            sum += __shfl_xor(sum, 2);
            sum += __shfl_xor(sum, 4);
            sum += __shfl_xor(sum, 8);
            lrun[r] = lrun[r] * al[r] + sum;
        }

        // rescale O, then O += P V
        const s8v pf0 = *(const s8v*)&Pb[w * 1152 + n16 * 72 + q4 * 8];
        const s8v pf1 = *(const s8v*)&Pb[w * 1152 + n16 * 72 + 32 + q4 * 8];
        #pragma unroll
        for (int t4 = 0; t4 < 4; t4++) {
            f4v o = O[t4];
            #pragma unroll
            for (int r = 0; r < 4; r++) o[r] *= al[r];
            const s8v v0 = *(const s8v*)&Vf[((t4 * 2 + 0) * 64 + lane) * 8];
            const s8v v1 = *(const s8v*)&Vf[((t4 * 2 + 1) * 64 + lane) * 8];
            o = __builtin_amdgcn_mfma_f32_16x16x32_bf16(pf0, v0, o, 0, 0, 0);
            o = __builtin_amdgcn_mfma_f32_16x16x32_bf16(pf1, v1, o, 0, 0, 0);
            O[t4] = o;
        }
    }

    float inv[4];
    #pragma unroll
    for (int r = 0; r < 4; r++) inv[r] = 1.0f / lrun[r];
    float* op = attn_out + (size_t)bh * L_SEQ * HD;
    #pragma unroll
    for (int r = 0; r < 4; r++) {
        const size_t row = (size_t)(rowbase + r) * HD;
        #pragma unroll
        for (int t4 = 0; t4 < 4; t4++)
            op[row + t4 * 16 + n16] = O[t4][r] * inv[r];
    }
}

// ==================================================================
// Output projection + bias + residual (fp32, R3-validated). grid (36,8,2), 256.
__global__ __launch_bounds__(256) void out_gemm(
    const float* __restrict__ attn, const float* __restrict__ Wo,
    const float* __restrict__ bo, const float* __restrict__ x,
    float* __restrict__ y)
{
    const int l0 = blockIdx.x * 64;
    const int o0 = blockIdx.y * 64;
    const int b  = blockIdx.z;

    __shared__ float As[16][68];
    __shared__ float Xs[16][68];

    const int t  = threadIdx.x;
    const int ti = t & 15;
    const int tj = t >> 4;
    float acc[4][4] = {};

    const float* ab = attn + (size_t)b * NHEADS * L_SEQ * HD;

    for (int c0 = 0; c0 < CDIM; c0 += 16) {
        {
            const int oi = t >> 2;
            const int cc = (t & 3) * 4;
            const float4 wv = *(const float4*)&Wo[(size_t)(o0 + oi) * CDIM + c0 + cc];
            As[cc + 0][oi] = wv.x;
            As[cc + 1][oi] = wv.y;
            As[cc + 2][oi] = wv.z;
            As[cc + 3][oi] = wv.w;
        }
        {
            const int j   = t & 63;
            const int kkb = (t >> 6) * 4;
            const int c   = c0 + kkb;
            const int hh  = c >> 6;
            const int dd  = c & 63;
            const float4 av = *(const float4*)&ab[((size_t)hh * L_SEQ + l0 + j) * HD + dd];
            Xs[kkb + 0][j] = av.x;
            Xs[kkb + 1][j] = av.y;
            Xs[kkb + 2][j] = av.z;
            Xs[kkb + 3][j] = av.w;
        }
        __syncthreads();
        #pragma unroll
        for (int kk = 0; kk < 16; kk++) {
            const float4 a  = *(const float4*)&As[kk][ti * 4];
            const float4 bb = *(const float4*)&Xs[kk][tj * 4];
            const float av[4] = {a.x, a.y, a.z, a.w};
            const float bv4[4] = {bb.x, bb.y, bb.z, bb.w};
            #pragma unroll
            for (int i = 0; i < 4; i++)
                #pragma unroll
                for (int j = 0; j < 4; j++)
                    acc[i][j] += av[i] * bv4[j];
        }
        __syncthreads();
    }

    const float4 bi = *(const float4*)&bo[o0 + ti * 4];
    const float bia[4] = {bi.x, bi.y, bi.z, bi.w};
    #pragma unroll
    for (int i = 0; i < 4; i++) {
        const int o = o0 + ti * 4 + i;
        const size_t off = ((size_t)b * CDIM + o) * L_SEQ + l0 + tj * 4;
        const float4 xv = *(const float4*)&x[off];
        float4 st;
        st.x = acc[i][0] + bia[i] + xv.x;
        st.y = acc[i][1] + bia[i] + xv.y;
        st.z = acc[i][2] + bia[i] + xv.z;
        st.w = acc[i][3] + bia[i] + xv.w;
        *(float4*)&y[off] = st;
    }
}

// ==================================================================
__global__ __launch_bounds__(256) void ln_kernel(
    float* __restrict__ y, const float* __restrict__ gamma,
    const float* __restrict__ beta)
{
    const int t  = threadIdx.x;
    const int pi = t & 63;
    const int g  = t >> 6;
    const int pos = blockIdx.x * 64 + pi;
    const int b = (pos >= L_SEQ) ? 1 : 0;
    const int l = pos - b * L_SEQ;
    float* col = y + (size_t)b * CDIM * L_SEQ + l;

    float s = 0.f, sq = 0.f;
    for (int c = g * 128; c < g * 128 + 128; c++) {
        const float v = col[(size_t)c * L_SEQ];
        s += v; sq += v * v;
    }
    __shared__ float S1[4][64];
    __shared__ float S2[4][64];
    S1[g][pi] = s; S2[g][pi] = sq;
    __syncthreads();
    if (g == 0) {
        s  = S1[0][pi] + S1[1][pi] + S1[2][pi] + S1[3][pi];
        sq = S2[0][pi] + S2[1][pi] + S2[2][pi] + S2[3][pi];
        const float mu = s * (1.0f / CDIM);
        const float var = sq * (1.0f / CDIM) - mu * mu;
        S1[0][pi] = mu;
        S2[0][pi] = rsqrtf(var + 1e-5f);
    }
    __syncthreads();
    const float mu = S1[0][pi];
    const float rs = S2[0][pi];
    for (int c = g * 128; c < g * 128 + 128; c++) {
        const float v = col[(size_t)c * L_SEQ];
        col[(size_t)c * L_SEQ] = (v - mu) * rs * gamma[c] + beta[c];
    }
}

// ==================================================================
extern "C" void kernel_launch(void* const* d_in, const int* in_sizes, int n_in,
                              void* d_out, int out_size, void* d_ws, size_t ws_size,
                              hipStream_t stream) {
    const float* x    = (const float*)d_in[0];
    const int* mask   = (const int*)d_in[1];
    const float* pos  = (const float*)d_in[2];
    const float* Wq   = (const float*)d_in[3];
    const float* bq   = (const float*)d_in[4];
    const float* Wk   = (const float*)d_in[5];
    const float* bk   = (const float*)d_in[6];
    const float* Wv   = (const float*)d_in[7];
    const float* bv   = (const float*)d_in[8];
    const float* Wo   = (const float*)d_in[9];
    const float* bo   = (const float*)d_in[10];
    const float* rel  = (const float*)d_in[11];
    const float* gam  = (const float*)d_in[12];
    const float* bet  = (const float*)d_in[13];

    const size_t per = (size_t)2 * NHEADS * L_SEQ * HD;  // 2359296 elems
    ushort* qw  = (ushort*)d_ws;
    ushort* kw  = qw + per;
    ushort* vw  = kw + per;
    ushort* xth = vw + per;
    ushort* xtl = xth + per;
    ushort* wbh = xtl + per;                    // 4*512*512
    ushort* wbl = wbh + (size_t)4 * CDIM * CDIM;
    float* attn = (float*)xth;   // overlay: per floats == xth+xtl bytes exactly
    float* y = (float*)d_out;

    conv_w<<<dim3(128, 4), 256, 0, stream>>>(Wq, Wk, Wv, Wo, wbh, wbl);
    prep_xt<<<dim3(36, 8, 2), 256, 0, stream>>>(x, pos, xth, xtl);
    qkv_mfma<<<dim3(36, 24, 2), 256, 0, stream>>>(wbh, wbl, xth, xtl, bq, bk, bv, qw, kw, vw);
    flash_attn_mfma<<<dim3(576), 256, 0, stream>>>(qw, kw, vw, mask, rel, attn);
    out_gemm<<<dim3(36, 8, 2), 256, 0, stream>>>(attn, Wo, bo, x, y);
    ln_kernel<<<(2 * L_SEQ) / 64, 256, 0, stream>>>(y, gam, bet);
}